// Round 1
// baseline (1076.860 us; speedup 1.0000x reference)
//
#include <hip/hip_runtime.h>
#include <cstdint>
#include <cstddef>

// Problem: B=16, S=2048, IN=1024, OUT=4096
// out[b,s,o] = sum_i x[b,s,i]*(W[o,i]-lr_b*G[o,i]) + bias[o]-lr_b*pbias[o]
#define PB   16
#define SEQ  2048
#define KIN  1024
#define NOUT 4096

#define BM 256
#define BN 256
#define BK 64
#define NKT (KIN / BK)   // 16 K-tiles

typedef __bf16 bf16x8 __attribute__((ext_vector_type(8)));
typedef float  f32x4  __attribute__((ext_vector_type(4)));

__device__ __forceinline__ unsigned short f2bf(float f) {
  union { float f; uint32_t u; } v; v.f = f;
  uint32_t u = v.u;
  u += 0x7fffu + ((u >> 16) & 1u);   // RNE
  return (unsigned short)(u >> 16);
}

__device__ __forceinline__ void async_copy16(const unsigned short* g, unsigned short* l) {
  __builtin_amdgcn_global_load_lds(
      (const __attribute__((address_space(1))) unsigned int*)g,
      (__attribute__((address_space(3))) unsigned int*)l,
      16, 0, 0);
}

// ---- kernel 1: x fp32 -> bf16 (8 elems/thread) ----------------------------
__global__ __launch_bounds__(256) void cvt_x_kernel(const float* __restrict__ x,
                                                    unsigned short* __restrict__ xb) {
  size_t i = ((size_t)blockIdx.x * 256 + threadIdx.x) * 8;
  float4 a = *(const float4*)(x + i);
  float4 b = *(const float4*)(x + i + 4);
  union { unsigned short s[8]; uint4 v; } p;
  p.s[0] = f2bf(a.x); p.s[1] = f2bf(a.y); p.s[2] = f2bf(a.z); p.s[3] = f2bf(a.w);
  p.s[4] = f2bf(b.x); p.s[5] = f2bf(b.y); p.s[6] = f2bf(b.z); p.s[7] = f2bf(b.w);
  *(uint4*)(xb + i) = p.v;
}

// ---- kernel 2: Wc[b][o][i] = bf16(W[o][i] - lr_b*G[o][i]), b innermost ----
__global__ __launch_bounds__(256) void cvt_w_kernel(const float* __restrict__ W,
                                                    const float* __restrict__ G,
                                                    const float* __restrict__ lrs,
                                                    unsigned short* __restrict__ wc) {
  size_t e = ((size_t)blockIdx.x * 256 + threadIdx.x) * 8;  // elem offset in [4096*1024]
  float4 w0 = *(const float4*)(W + e);
  float4 w1 = *(const float4*)(W + e + 4);
  float4 g0 = *(const float4*)(G + e);
  float4 g1 = *(const float4*)(G + e + 4);
  #pragma unroll
  for (int b = 0; b < PB; ++b) {
    float lr = lrs[b];
    union { unsigned short s[8]; uint4 v; } p;
    p.s[0] = f2bf(w0.x - lr * g0.x); p.s[1] = f2bf(w0.y - lr * g0.y);
    p.s[2] = f2bf(w0.z - lr * g0.z); p.s[3] = f2bf(w0.w - lr * g0.w);
    p.s[4] = f2bf(w1.x - lr * g1.x); p.s[5] = f2bf(w1.y - lr * g1.y);
    p.s[6] = f2bf(w1.z - lr * g1.z); p.s[7] = f2bf(w1.w - lr * g1.w);
    *(uint4*)(wc + (size_t)b * (size_t)NOUT * KIN + e) = p.v;
  }
}

// ---- kernel 3: batched GEMM out[b] = Xb @ Wc[b]^T + bias_eff --------------
// 256x256 tile, BK=64, 8 waves (2M x 4N), 128 KiB double-buffered LDS.
// T2: XOR swizzle byte^=(row&7)<<4 (pre-swizzled global src, linear LDS dest,
//     swizzled ds_read) -> conflict-free column-slice reads.
// T3/T4: counted vmcnt(8) at tile boundaries only; next tile's 8 loads stay
//     in flight across all phase barriers. vmcnt(0) only on the last tile.
// T5: setprio(1) around each 16-MFMA cluster.
// T1: bijective XCD swizzle on 1-D grid (2048 % 8 == 0).
__global__ __launch_bounds__(512, 2) void gemm_kernel(
    const unsigned short* __restrict__ xb,   // [16][2048][1024] bf16
    const unsigned short* __restrict__ wc,   // [16][4096][1024] bf16
    const float* __restrict__ bias,          // [4096]
    const float* __restrict__ pbias,         // [4096]
    const float* __restrict__ lrs,           // [16]
    float* __restrict__ out)                 // [16][2048][4096] fp32
{
  const int tid  = threadIdx.x;
  const int wave = tid >> 6;
  const int lane = tid & 63;
  const int quad = lane >> 4;
  const int l16  = lane & 15;
  const int wm   = wave >> 2;   // M half (0..1)  -> rows wm*128..+128
  const int wn   = wave & 3;    // N strip (0..3) -> cols wn*64..+64

  // XCD-aware bijective swizzle: 2048 blocks, 8 XCDs, 256 contiguous wg/XCD
  const int orig = blockIdx.x;
  const int wg   = (orig & 7) * (2048 / 8) + (orig >> 3);
  const int nt = wg & 15;          // 16 OUT tiles
  const int mt = (wg >> 4) & 7;    // 8 SEQ tiles
  const int b  = wg >> 7;          // 16 batches

  __shared__ alignas(16) unsigned short As[2][2][128][64];  // [dbuf][half][row][col] 64 KiB
  __shared__ alignas(16) unsigned short Bs[2][2][128][64];  // 64 KiB

  const unsigned short* xA = xb + ((size_t)b * SEQ  + (size_t)mt * BM) * KIN;
  const unsigned short* wB = wc + ((size_t)b * NOUT + (size_t)nt * BN) * KIN;

  // Staging: thread -> (row srow of 64-row issue, 16B chunk), source chunk
  // pre-swizzled so linear LDS dest + swizzled read = involution (rule #21).
  const int srow = tid >> 3;                       // 0..63
  const int sx   = (tid & 7) ^ (srow & 7);         // swizzled 16B chunk
  const unsigned short* gA = xA + (size_t)srow * KIN + sx * 8;
  const unsigned short* gB = wB + (size_t)srow * KIN + sx * 8;

  // 8 global_load_lds per thread per K-tile (A: 2 halves x 2 issues, B same)
#define STAGE(d, k0)                                                          \
  do {                                                                        \
    _Pragma("unroll") for (int h = 0; h < 2; ++h) {                           \
      _Pragma("unroll") for (int i = 0; i < 2; ++i) {                         \
        async_copy16(gA + (size_t)(h * 128 + i * 64) * KIN + (k0),            \
                     &As[d][h][i * 64 + wave * 8][0]);                        \
        async_copy16(gB + (size_t)(h * 128 + i * 64) * KIN + (k0),            \
                     &Bs[d][h][i * 64 + wave * 8][0]);                        \
      }                                                                       \
    }                                                                         \
  } while (0)

  // fragment read offsets (bytes). row stride 128B; swizzle XOR on bits 4-6.
  const int aoff = l16 * 128;
  const int boff = (wn & 1) * 8192 + l16 * 128;
  const int xs   = (l16 & 7) << 4;
  const int ck0  = (quad * 16) ^ xs;          // kstep 0
  const int ck1  = (64 + quad * 16) ^ xs;     // kstep 1

  const char* aH0 = (const char*)&As[0][wm][0][0];
  const char* aH1 = (const char*)&As[1][wm][0][0];
  const char* bH0 = (const char*)&Bs[0][wn >> 1][0][0];
  const char* bH1 = (const char*)&Bs[1][wn >> 1][0][0];

  f32x4 acc[8][4];
  #pragma unroll
  for (int i = 0; i < 8; ++i)
    #pragma unroll
    for (int j = 0; j < 4; ++j)
      acc[i][j] = (f32x4){0.f, 0.f, 0.f, 0.f};

  // 4 phases per K-tile: (kk, mh). 12 or 8 ds_read_b128, then 16 MFMA.
#define COMPUTE(AH, BH)                                                       \
  {                                                                           \
    _Pragma("unroll") for (int kk = 0; kk < 2; ++kk) {                        \
      const int ck = kk ? ck1 : ck0;                                          \
      bf16x8 bfr[4];                                                          \
      _Pragma("unroll") for (int mh = 0; mh < 2; ++mh) {                      \
        bf16x8 af[4];                                                         \
        _Pragma("unroll") for (int j = 0; j < 4; ++j)                         \
          af[j] = *(const bf16x8*)((AH) + aoff + (mh * 4 + j) * 2048 + ck);   \
        if (mh == 0) {                                                        \
          _Pragma("unroll") for (int n = 0; n < 4; ++n)                       \
            bfr[n] = *(const bf16x8*)((BH) + boff + n * 2048 + ck);           \
        }                                                                     \
        __builtin_amdgcn_s_barrier();                                         \
        asm volatile("s_waitcnt lgkmcnt(0)" ::: "memory");                    \
        __builtin_amdgcn_sched_barrier(0);                                    \
        __builtin_amdgcn_s_setprio(1);                                        \
        _Pragma("unroll") for (int j = 0; j < 4; ++j)                         \
          _Pragma("unroll") for (int n = 0; n < 4; ++n)                       \
            acc[mh * 4 + j][n] = __builtin_amdgcn_mfma_f32_16x16x32_bf16(     \
                af[j], bfr[n], acc[mh * 4 + j][n], 0, 0, 0);                  \
        __builtin_amdgcn_s_setprio(0);                                        \
        __builtin_amdgcn_sched_barrier(0);                                    \
        __builtin_amdgcn_s_barrier();                                         \
      }                                                                       \
    }                                                                         \
  }

  STAGE(0, 0);                         // tile 0 -> buf0 (8 loads in flight)
  #pragma unroll 1
  for (int t = 0; t < NKT; t += 2) {
    // tile t in buf0; stage tile t+1 into buf1 (buf1's last reads ended at
    // the previous iteration's final phase barrier)
    STAGE(1, (t + 1) * BK);
    asm volatile("s_waitcnt vmcnt(8)" ::: "memory");  // tile t landed; t+1 in flight
    __builtin_amdgcn_sched_barrier(0);
    __builtin_amdgcn_s_barrier();
    COMPUTE(aH0, bH0);
    __builtin_amdgcn_sched_barrier(0);

    // tile t+1 in buf1; stage tile t+2 into buf0 (just fully read)
    if (t + 2 < NKT) {
      STAGE(0, (t + 2) * BK);
      asm volatile("s_waitcnt vmcnt(8)" ::: "memory");
    } else {
      asm volatile("s_waitcnt vmcnt(0)" ::: "memory");
    }
    __builtin_amdgcn_sched_barrier(0);
    __builtin_amdgcn_s_barrier();
    COMPUTE(aH1, bH1);
    __builtin_amdgcn_sched_barrier(0);
  }
#undef STAGE
#undef COMPUTE

  // epilogue: C/D layout col=lane&15, row=quad*4+reg (m89-verified)
  const float lr = lrs[b];
  const int row0 = mt * BM + wm * 128;
  const int col0 = nt * BN + wn * 64;
  float* outB = out + (size_t)b * SEQ * NOUT;
  #pragma unroll
  for (int fn = 0; fn < 4; ++fn) {
    const int o = col0 + fn * 16 + l16;
    const float be = bias[o] - lr * pbias[o];
    #pragma unroll
    for (int fm = 0; fm < 8; ++fm) {
      const int r0 = row0 + fm * 16 + quad * 4;
      #pragma unroll
      for (int r = 0; r < 4; ++r)
        outB[(size_t)(r0 + r) * NOUT + o] = acc[fm][fn][r] + be;
    }
  }
}

extern "C" void kernel_launch(void* const* d_in, const int* in_sizes, int n_in,
                              void* d_out, int out_size, void* d_ws, size_t ws_size,
                              hipStream_t stream) {
  const float* x     = (const float*)d_in[0];  // [16,2048,1024]
  const float* W     = (const float*)d_in[1];  // [4096,1024]
  const float* bias  = (const float*)d_in[2];  // [4096]
  const float* G     = (const float*)d_in[3];  // [4096,1024]
  const float* pb    = (const float*)d_in[4];  // [4096]
  const float* lrs   = (const float*)d_in[5];  // [16]
  float* out = (float*)d_out;

  // workspace layout: xb (64 MiB bf16) | wc (128 MiB bf16) = 192 MiB
  unsigned short* xb = (unsigned short*)d_ws;
  unsigned short* wc = xb + (size_t)PB * SEQ * KIN;

  cvt_x_kernel<<<16384, 256, 0, stream>>>(x, xb);
  cvt_w_kernel<<<2048, 256, 0, stream>>>(W, G, lrs, wc);

  // 2048 blocks (16 nt x 8 mt x 16 b), 512 threads, 1 block/CU (128 KiB LDS)
  gemm_kernel<<<2048, 512, 0, stream>>>(xb, wc, bias, pb, lrs, out);
}

// Round 2
// 1007.794 us; speedup vs baseline: 1.0685x; 1.0685x over previous
//
#include <hip/hip_runtime.h>
#include <cstdint>
#include <cstddef>

// Problem: B=16, S=2048, IN=1024, OUT=4096
// out[b,s,o] = sum_i x[b,s,i]*(W[o,i]-lr_b*G[o,i]) + bias[o]-lr_b*pbias[o]
#define PB   16
#define SEQ  2048
#define KIN  1024
#define NOUT 4096

#define BM 256
#define BN 256
#define BK 64
#define NKT (KIN / BK)   // 16 K-tiles

typedef __bf16 bf16x8 __attribute__((ext_vector_type(8)));
typedef float  f32x4  __attribute__((ext_vector_type(4)));

__device__ __forceinline__ unsigned short f2bf(float f) {
  union { float f; uint32_t u; } v; v.f = f;
  uint32_t u = v.u;
  u += 0x7fffu + ((u >> 16) & 1u);   // RNE
  return (unsigned short)(u >> 16);
}

__device__ __forceinline__ void async_copy16(const unsigned short* g, unsigned short* l) {
  __builtin_amdgcn_global_load_lds(
      (const __attribute__((address_space(1))) unsigned int*)g,
      (__attribute__((address_space(3))) unsigned int*)l,
      16, 0, 0);
}

// ---- kernel 1: x fp32 -> bf16 (8 elems/thread) ----------------------------
__global__ __launch_bounds__(256) void cvt_x_kernel(const float* __restrict__ x,
                                                    unsigned short* __restrict__ xb) {
  size_t i = ((size_t)blockIdx.x * 256 + threadIdx.x) * 8;
  float4 a = *(const float4*)(x + i);
  float4 b = *(const float4*)(x + i + 4);
  union { unsigned short s[8]; uint4 v; } p;
  p.s[0] = f2bf(a.x); p.s[1] = f2bf(a.y); p.s[2] = f2bf(a.z); p.s[3] = f2bf(a.w);
  p.s[4] = f2bf(b.x); p.s[5] = f2bf(b.y); p.s[6] = f2bf(b.z); p.s[7] = f2bf(b.w);
  *(uint4*)(xb + i) = p.v;
}

// ---- kernel 2: Wc[b][o][i] = bf16(W[o][i] - lr_b*G[o][i]), b innermost ----
__global__ __launch_bounds__(256) void cvt_w_kernel(const float* __restrict__ W,
                                                    const float* __restrict__ G,
                                                    const float* __restrict__ lrs,
                                                    unsigned short* __restrict__ wc) {
  size_t e = ((size_t)blockIdx.x * 256 + threadIdx.x) * 8;  // elem offset in [4096*1024]
  float4 w0 = *(const float4*)(W + e);
  float4 w1 = *(const float4*)(W + e + 4);
  float4 g0 = *(const float4*)(G + e);
  float4 g1 = *(const float4*)(G + e + 4);
  #pragma unroll
  for (int b = 0; b < PB; ++b) {
    float lr = lrs[b];
    union { unsigned short s[8]; uint4 v; } p;
    p.s[0] = f2bf(w0.x - lr * g0.x); p.s[1] = f2bf(w0.y - lr * g0.y);
    p.s[2] = f2bf(w0.z - lr * g0.z); p.s[3] = f2bf(w0.w - lr * g0.w);
    p.s[4] = f2bf(w1.x - lr * g1.x); p.s[5] = f2bf(w1.y - lr * g1.y);
    p.s[6] = f2bf(w1.z - lr * g1.z); p.s[7] = f2bf(w1.w - lr * g1.w);
    *(uint4*)(wc + (size_t)b * (size_t)NOUT * KIN + e) = p.v;
  }
}

// ---- kernel 3: batched GEMM out[b] = Xb @ Wc[b]^T + bias_eff --------------
// m201 8-phase schedule, plain HIP:
//  256x256 tile, BK=64, 8 waves (2M x 4N), per-wave C = 128x64.
//  Phases per K-tile = per-wave C-quadrants (mq,nq): (0,0)->(0,1)->(1,1)->(1,0),
//  B-quadrant regs held for reuse (b0 spans P0..P3, b1 spans P1..P2).
//  LDS quarters As[d][mq][128][64], Bs[d][nq][128][64]; each quarter dead
//  after the phase that ds_reads it -> staging runs 3 quarters ahead:
//    t.P0 stages (t+1).qA1 ; t.P1/P2/P3 stage (t+2).qA0/qB0/qB1 into the
//    current buffer's dead regions.  vmcnt(6) once per tile at P3.
//  T2 XOR swizzle (16B chunk ^ row&7) on global src + ds_read; T5 setprio.
__global__ __launch_bounds__(512, 2) void gemm_kernel(
    const unsigned short* __restrict__ xb,   // [16][2048][1024] bf16
    const unsigned short* __restrict__ wc,   // [16][4096][1024] bf16
    const float* __restrict__ bias,          // [4096]
    const float* __restrict__ pbias,         // [4096]
    const float* __restrict__ lrs,           // [16]
    float* __restrict__ out)                 // [16][2048][4096] fp32
{
  const int tid  = threadIdx.x;
  const int wave = tid >> 6;
  const int lane = tid & 63;
  const int quad = lane >> 4;
  const int l16  = lane & 15;
  const int wm   = wave >> 2;   // M half (0..1)  -> rows wm*128..+128
  const int wn   = wave & 3;    // N strip (0..3) -> cols wn*64..+64

  // XCD-aware bijective swizzle: 2048 blocks, 8 XCDs, 256 contiguous wg/XCD
  const int orig = blockIdx.x;
  const int wg   = (orig & 7) * (2048 / 8) + (orig >> 3);
  const int nt = wg & 15;          // 16 OUT tiles
  const int mt = (wg >> 4) & 7;    // 8 SEQ tiles
  const int b  = wg >> 7;          // 16 batches

  // [dbuf][quarter][128 region-rows][64 K] ; A-quarter mq: region row rr maps
  // to phys A row (rr>>6)*128 + mq*64 + (rr&63); B-quarter nq: phys B row
  // (rr>>5)*64 + nq*32 + (rr&31).
  __shared__ alignas(16) unsigned short As[2][2][128][64];  // 64 KiB
  __shared__ alignas(16) unsigned short Bs[2][2][128][64];  // 64 KiB

  const unsigned short* xA = xb + ((size_t)b * SEQ  + (size_t)mt * BM) * KIN;
  const unsigned short* wB = wc + ((size_t)b * NOUT + (size_t)nt * BN) * KIN;

  // staging: srow = tid>>3 (0..63), chunk sx pre-swizzled (involution with read)
  const int srow = tid >> 3;
  const int sx   = (tid & 7) ^ (srow & 7);
  const unsigned short* gA = xA + (size_t)srow * KIN + sx * 8;
  const unsigned short* gB = wB + (size_t)(((srow >> 5) * 64) + (srow & 31)) * KIN + sx * 8;

  // 2 loads per quarter per thread; LDS dest wave-uniform base + lane*16
#define STAGE_A(d, mq, k0) do {                                               \
    async_copy16(gA + (size_t)((mq) * 64) * KIN + (k0),                       \
                 &As[d][mq][wave * 8][0]);                                    \
    async_copy16(gA + (size_t)(128 + (mq) * 64) * KIN + (k0),                 \
                 &As[d][mq][64 + wave * 8][0]);                               \
  } while (0)
#define STAGE_B(d, nq, k0) do {                                               \
    async_copy16(gB + (size_t)((nq) * 32) * KIN + (k0),                       \
                 &Bs[d][nq][wave * 8][0]);                                    \
    async_copy16(gB + (size_t)(128 + (nq) * 32) * KIN + (k0),                 \
                 &Bs[d][nq][64 + wave * 8][0]);                               \
  } while (0)

  // fragment read offsets (bytes); region row stride 128 B
  const int xs    = (l16 & 7) << 4;
  const int kcol0 = (quad * 16) ^ xs;          // kk=0
  const int kcol1 = (64 + quad * 16) ^ xs;     // kk=1
  const int aoff  = (wm * 64 + l16) * 128;     // + j*2048 + mq-region
  const int boff  = (wn * 32 + l16) * 128;     // + n*2048 + nq-region

  f32x4 acc[8][4];
  #pragma unroll
  for (int i = 0; i < 8; ++i)
    #pragma unroll
    for (int j = 0; j < 4; ++j)
      acc[i][j] = (f32x4){0.f, 0.f, 0.f, 0.f};

  bf16x8 af[2][4];   // A quadrant (mq), both kk
  bf16x8 b0[2][2];   // B quadrant nq=0, held P0..P3
  bf16x8 b1[2][2];   // B quadrant nq=1, held P1..P2

#define READ_A(c, mq)                                                         \
  {                                                                           \
    const char* aR = (const char*)&As[c][mq][0][0];                           \
    _Pragma("unroll") for (int j = 0; j < 4; ++j) {                           \
      af[0][j] = *(const bf16x8*)(aR + aoff + j * 2048 + kcol0);              \
      af[1][j] = *(const bf16x8*)(aR + aoff + j * 2048 + kcol1);              \
    }                                                                         \
  }
#define READ_B(c, nq, BV)                                                     \
  {                                                                           \
    const char* bR = (const char*)&Bs[c][nq][0][0];                           \
    _Pragma("unroll") for (int n = 0; n < 2; ++n) {                           \
      BV[0][n] = *(const bf16x8*)(bR + boff + n * 2048 + kcol0);              \
      BV[1][n] = *(const bf16x8*)(bR + boff + n * 2048 + kcol1);              \
    }                                                                         \
  }
  // barrier -> lgkm drain -> sched fence (rule #18) -> prio-wrapped 16 MFMA
#define PHASE_MFMA(AR, AC, BV)                                                \
  __builtin_amdgcn_s_barrier();                                               \
  asm volatile("s_waitcnt lgkmcnt(0)" ::: "memory");                          \
  __builtin_amdgcn_sched_barrier(0);                                          \
  __builtin_amdgcn_s_setprio(1);                                              \
  _Pragma("unroll") for (int kk = 0; kk < 2; ++kk)                            \
    _Pragma("unroll") for (int j = 0; j < 4; ++j)                             \
      _Pragma("unroll") for (int n = 0; n < 2; ++n)                           \
        acc[(AR) + j][(AC) + n] = __builtin_amdgcn_mfma_f32_16x16x32_bf16(    \
            af[kk][j], BV[kk][n], acc[(AR) + j][(AC) + n], 0, 0, 0);          \
  __builtin_amdgcn_s_setprio(0);                                              \
  __builtin_amdgcn_s_barrier();

  // ---- prologue: tile0 fully + tile1 quarters q0..q2 (14 loads) ----------
  STAGE_A(0, 0, 0);        // t0.qA0
  STAGE_B(0, 0, 0);        // t0.qB0
  STAGE_B(0, 1, 0);        // t0.qB1
  STAGE_A(0, 1, 0);        // t0.qA1
  STAGE_A(1, 0, BK);       // t1.qA0
  STAGE_B(1, 0, BK);       // t1.qB0
  STAGE_B(1, 1, BK);       // t1.qB1
  asm volatile("s_waitcnt vmcnt(6)" ::: "memory");   // t0 landed; t1 3/4 in flight
  __builtin_amdgcn_sched_barrier(0);
  __builtin_amdgcn_s_barrier();

  #pragma unroll 1
  for (int t = 0; t < NKT; ++t) {
    const int c = t & 1;
    // ---- P0: quadrant (0,0) -------------------------------------------
    if (t + 1 < NKT) STAGE_A(c ^ 1, 1, (t + 1) * BK);   // (t+1).qA1
    READ_A(c, 0);
    READ_B(c, 0, b0);
    PHASE_MFMA(0, 0, b0)
    // ---- P1: quadrant (0,1) -------------------------------------------
    if (t + 2 < NKT) STAGE_A(c, 0, (t + 2) * BK);       // (t+2).qA0 (dead region)
    READ_B(c, 1, b1);
    PHASE_MFMA(0, 2, b1)
    // ---- P2: quadrant (1,1) -------------------------------------------
    if (t + 2 < NKT) STAGE_B(c, 0, (t + 2) * BK);       // (t+2).qB0
    READ_A(c, 1);
    PHASE_MFMA(4, 2, b1)
    // ---- P3: quadrant (1,0), regs only; tile-boundary vmcnt ------------
    if (t + 2 < NKT) {
      STAGE_B(c, 1, (t + 2) * BK);                      // (t+2).qB1
      asm volatile("s_waitcnt vmcnt(6)" ::: "memory");  // tile t+1 fully landed
    } else {
      asm volatile("s_waitcnt vmcnt(0)" ::: "memory");
    }
    __builtin_amdgcn_sched_barrier(0);
    PHASE_MFMA(4, 0, b0)
  }
#undef STAGE_A
#undef STAGE_B
#undef READ_A
#undef READ_B
#undef PHASE_MFMA

  // epilogue: C/D layout col=lane&15, row=quad*4+reg (m89-verified)
  const float lr = lrs[b];
  const int row0 = mt * BM + wm * 128;
  const int col0 = nt * BN + wn * 64;
  float* outB = out + (size_t)b * SEQ * NOUT;
  #pragma unroll
  for (int fn = 0; fn < 4; ++fn) {
    const int o = col0 + fn * 16 + l16;
    const float be = bias[o] - lr * pbias[o];
    #pragma unroll
    for (int fm = 0; fm < 8; ++fm) {
      const int r0 = row0 + fm * 16 + quad * 4;
      #pragma unroll
      for (int r = 0; r < 4; ++r)
        outB[(size_t)(r0 + r) * NOUT + o] = acc[fm][fn][r] + be;
    }
  }
}

extern "C" void kernel_launch(void* const* d_in, const int* in_sizes, int n_in,
                              void* d_out, int out_size, void* d_ws, size_t ws_size,
                              hipStream_t stream) {
  const float* x     = (const float*)d_in[0];  // [16,2048,1024]
  const float* W     = (const float*)d_in[1];  // [4096,1024]
  const float* bias  = (const float*)d_in[2];  // [4096]
  const float* G     = (const float*)d_in[3];  // [4096,1024]
  const float* pb    = (const float*)d_in[4];  // [4096]
  const float* lrs   = (const float*)d_in[5];  // [16]
  float* out = (float*)d_out;

  // workspace layout: xb (64 MiB bf16) | wc (128 MiB bf16) = 192 MiB
  unsigned short* xb = (unsigned short*)d_ws;
  unsigned short* wc = xb + (size_t)PB * SEQ * KIN;

  cvt_x_kernel<<<16384, 256, 0, stream>>>(x, xb);
  cvt_w_kernel<<<2048, 256, 0, stream>>>(W, G, lrs, wc);

  // 2048 blocks (16 nt x 8 mt x 16 b), 512 threads, 1 block/CU (128 KiB LDS)
  gemm_kernel<<<2048, 512, 0, stream>>>(xb, wc, bias, pb, lrs, out);
}